// Round 4
// baseline (424.462 us; speedup 1.0000x reference)
//
#include <hip/hip_runtime.h>

typedef __attribute__((ext_vector_type(8))) __bf16 bf16x8;
typedef __attribute__((ext_vector_type(4))) __bf16 bf16x4;
typedef __attribute__((ext_vector_type(4))) float floatx4;

#define MFMA16x16x32 __builtin_amdgcn_mfma_f32_16x16x32_bf16

// async 16B/lane global->LDS; LDS dest = wave-uniform base + lane*16.
__device__ __forceinline__ void async_load16(const void* g, void* l) {
  __builtin_amdgcn_global_load_lds((const __attribute__((address_space(1))) void*)g,
                                   (__attribute__((address_space(3))) void*)l, 16, 0, 0);
}

// ---------------- merged cast fp32 -> bf16 for all 5 inputs ----------------
__global__ __launch_bounds__(256) void cast_all_kernel(const float* __restrict__ x,
                                                       const float* __restrict__ wq,
                                                       const float* __restrict__ wk,
                                                       const float* __restrict__ wv,
                                                       const float* __restrict__ wo,
                                                       __bf16* __restrict__ dst) {
  int i = blockIdx.x * blockDim.x + threadIdx.x;  // float4 units
  const float* src;
  int off;
  if (i < 2097152)      { src = x;  off = 0; }
  else if (i < 3145728) { src = wq; off = 2097152; }
  else if (i < 3407872) { src = wk; off = 3145728; }
  else if (i < 3670016) { src = wv; off = 3407872; }
  else                  { src = wo; off = 3670016; }
  float4 v = ((const float4*)src)[i - off];
  bf16x4 o;
  o[0] = (__bf16)v.x; o[1] = (__bf16)v.y; o[2] = (__bf16)v.z; o[3] = (__bf16)v.w;
  *(bf16x4*)(dst + (size_t)i * 4) = o;
}

// ---------------- GEMM: C(M,N) = A(M,K) @ B(N,K)^T, bf16 in, m97-style ----------------
template <int MODE>
__global__ __launch_bounds__(256, 3) void gemm_bt(const __bf16* __restrict__ A,
                                                  const __bf16* __restrict__ Bw,
                                                  float* __restrict__ C,
                                                  const float* __restrict__ cs,
                                                  const float* __restrict__ sn,
                                                  __bf16* __restrict__ qb,
                                                  __bf16* __restrict__ kb,
                                                  __bf16* __restrict__ vtg,
                                                  int M, int N, int K) {
  __shared__ __bf16 As[128][64];
  __shared__ __bf16 Bs[128][64];
  const int tid = threadIdx.x;
  const int wave = tid >> 6, lane = tid & 63;
  const int quad = lane >> 4, l16 = lane & 15;
  const int wm = (wave >> 1) * 64, wn = (wave & 1) * 64;
  const int row0 = blockIdx.y * 128, col0 = blockIdx.x * 128;
  const int lr = lane >> 3, ls = lane & 7;
  const int segg = ls ^ lr;
  floatx4 acc[4][4] = {};
  const __bf16* Ab = A + (size_t)row0 * K + segg * 8;
  const __bf16* Bb = Bw + (size_t)col0 * K + segg * 8;
  for (int k0 = 0; k0 < K; k0 += 64) {
    __syncthreads();
#pragma unroll
    for (int i = 0; i < 4; i++) {
      int c = wave * 4 + i;
      int r = c * 8 + lr;
      async_load16(Ab + (size_t)r * K + k0, &As[c * 8][0]);
      async_load16(Bb + (size_t)r * K + k0, &Bs[c * 8][0]);
    }
    __syncthreads();
#pragma unroll
    for (int kk = 0; kk < 64; kk += 32) {
      bf16x8 af[4], bfr[4];
#pragma unroll
      for (int mt = 0; mt < 4; mt++) {
        int row = wm + mt * 16 + l16;
        int seg = ((kk >> 3) + quad) ^ (row & 7);
        af[mt] = *(const bf16x8*)&As[row][seg * 8];
      }
#pragma unroll
      for (int nt = 0; nt < 4; nt++) {
        int row = wn + nt * 16 + l16;
        int seg = ((kk >> 3) + quad) ^ (row & 7);
        bfr[nt] = *(const bf16x8*)&Bs[row][seg * 8];
      }
#pragma unroll
      for (int mt = 0; mt < 4; mt++)
#pragma unroll
        for (int nt = 0; nt < 4; nt++)
          acc[mt][nt] = MFMA16x16x32(af[mt], bfr[nt], acc[mt][nt], 0, 0, 0);
    }
  }
  if (MODE == 0) {
#pragma unroll
    for (int mt = 0; mt < 4; mt++)
#pragma unroll
      for (int nt = 0; nt < 4; nt++)
#pragma unroll
        for (int r = 0; r < 4; r++) {
          int row = row0 + wm + mt * 16 + quad * 4 + r;
          int col = col0 + wn + nt * 16 + l16;
          C[(size_t)row * N + col] = acc[mt][nt][r];
        }
  } else {
    // ---- Q / K epilogue (RoPE) ----
#pragma unroll
    for (int mt = 0; mt < 4; mt++)
#pragma unroll
      for (int nt = 0; nt < 4; nt++) {
        const int cbase = col0 + wn + nt * 16;
        if (cbase < 2560) {
          const int c = cbase + l16;
#pragma unroll
          for (int r = 0; r < 4; r++) {
            int row = row0 + wm + mt * 16 + quad * 4 + r;
            int t = row & 2047;
            float v = acc[mt][nt][r];
            float vp = __shfl_xor(v, 1);  // RoPE pair partner (col ^ 1)
            int i = (c & 127) >> 1;
            float co = cs[t * 64 + i], si = sn[t * 64 + i];
            float rv = v * co + ((c & 1) ? vp : -vp) * si;
            if (cbase < 2048) {           // Q, pre-scaled for exp2 softmax
              qb[(size_t)row * 2048 + c] = (__bf16)(rv * 0.1275411391f);
            } else {                      // K
              kb[(size_t)row * 512 + c - 2048] = (__bf16)rv;
            }
          }
        }
      }
    // ---- V epilogue: LDS transpose -> contiguous stores ----
    __syncthreads();
    __bf16* Vl = &As[0][0] + wave * 1024;  // 16 vd x 64 t per wave (2KB)
    const int brow = row0 + wm;
#pragma unroll
    for (int nt = 0; nt < 4; nt++) {
      const int cbase = col0 + wn + nt * 16;
      if (cbase >= 2560) {
#pragma unroll
        for (int mt = 0; mt < 4; mt++)
#pragma unroll
          for (int r = 0; r < 4; r++)
            Vl[l16 * 64 + mt * 16 + quad * 4 + r] = (__bf16)acc[mt][nt][r];
        asm volatile("" ::: "memory");
        const int vB = cbase - 2560;
#pragma unroll
        for (int p = 0; p < 4; p++) {
          int vdl = p * 4 + (lane >> 4);
          int tl = (lane & 15) * 4;
          bf16x4 val = *(const bf16x4*)&Vl[vdl * 64 + tl];
          *(bf16x4*)&vtg[((size_t)(brow >> 11) * 512 + vB + vdl) * 2048 +
                         (brow & 2047) + tl] = val;
        }
        asm volatile("" ::: "memory");
      }
    }
  }
}

// ---------------- Flash attention: intra-WG split-KV, 8 waves, causal GQA -----------
// 512 WGs x 512 thr. Waves = 4 heads x 2 KV-chunks; KVBLK=32. Chunk 0 owns blocks
// [0,nk/2), chunk 1 owns [nk/2,nk) (incl. diagonal). Worst sequential depth halves
// (32 half-iters ~ 16 old units). Partials merge intra-WG via LDS (Ks/Vt dead) --
// no cross-WG traffic, no fences. LDS exactly 80KB -> 2 WGs/CU; VGPR capped 128.
__global__ __launch_bounds__(512, 4) void attn_kernel(const __bf16* __restrict__ qb,
                                                      const __bf16* __restrict__ kb,
                                                      const __bf16* __restrict__ vtg,
                                                      __bf16* __restrict__ yb) {
  const int id = blockIdx.x;
  const int kvh = id & 3, b = (id >> 2) & 1;   // id&7 = group -> XCD-local K/V
  const int tile = id >> 3;                    // 0..63
  const int tid = threadIdx.x, wave = tid >> 6, lane = tid & 63;
  const int ck = wave >> 2, hw = wave & 3;     // chunk, head-within-group
  const int h = kvh * 4 + hw;
  const int quad = lane >> 4, l16 = lane & 15;
  const int q0 = tile * 32;
  const int nk = tile + 1;                     // 32-key blocks total
  const int c0 = nk >> 1;                      // chunk0: [0,c0)
  const int L = nk - c0;                       // chunk1: [c0,nk); L >= c0, L >= 1

  __shared__ __bf16 Ks[2][2][32][128];   // [buf][chunk][key][dim] 32 KB, swizzled
  __shared__ __bf16 Vt[2][128][64];      // [buf][dim][ck*32+key]  32 KB, swizzled
  __shared__ __bf16 Ps[8][2][16][32];    // per-wave P strips      16 KB

  const __bf16* kbase = kb + (size_t)b * 2048 * 512 + kvh * 128;
  const __bf16* vbase = vtg + ((size_t)b * 512 + kvh * 128) * 2048;

  // ---- staging pointers (K: global_load_lds; V: gload->swizzled ds_write) ----
  const int kl = lane >> 4, ks16 = lane & 15;
  const __bf16* ksrc[2]; char* kdst[2];
#pragma unroll
  for (int jj = 0; jj < 2; jj++) {
    int krow = hw * 8 + jj * 4 + kl;
    ksrc[jj] = kbase + (size_t)krow * 512 + (ks16 ^ (krow & 7)) * 8;
    kdst[jj] = (char*)Ks + ck * 8192 + (hw * 8 + jj * 4) * 256;  // wave-uniform
  }
  const int vdl = lane >> 2, vks = lane & 3;
  const __bf16* vsrc[2]; char* vdst[2];
#pragma unroll
  for (int jj = 0; jj < 2; jj++) {
    int d = hw * 32 + jj * 16 + vdl;
    vsrc[jj] = vbase + (size_t)d * 2048 + vks * 8;
    vdst[jj] = (char*)Vt + d * 128 + (((ck * 4 + vks) ^ (d & 7)) * 16);
  }

  // ---- hoisted compute bases ----
  const int u16 = (quad ^ (l16 & 3)) * 16;
  const int b2_64 = (l16 & 4) ? 64 : 0;
  char* const kA0 = (char*)Ks + ck * 8192 + l16 * 256 + u16 + b2_64;  // kc even
  char* const kB0 = kA0 + 64 - 2 * b2_64;                             // kc odd
  char* const vrd0 = (char*)Vt + l16 * 128 + u16 + ((ck ^ ((l16 >> 2) & 1)) ? 64 : 0);
  char* const psb = (char*)Ps + wave * 2048;
  char* const prd = psb + l16 * 64 + u16;                             // + mt*1024
  const int h3 = (l16 >> 3) & 1;
  char* const pwE = psb + quad * 256 + (l16 & 7) * 2 + h3 * 16;       // r even
  char* const pwO = psb + quad * 256 + (l16 & 7) * 2 + 16 - h3 * 16;  // r odd

  bf16x8 ones;
#pragma unroll
  for (int j = 0; j < 8; j++) ones[j] = (__bf16)1.0f;
  floatx4 o[2][8] = {};
  floatx4 lsum[2] = {};

  // ---- prologue: stage block g0 of own chunk into buf 0 ----
  {
    const int g0 = ck ? c0 : 0;
    bf16x8 v0 = *(const bf16x8*)(vsrc[0] + g0 * 32);
    bf16x8 v1 = *(const bf16x8*)(vsrc[1] + g0 * 32);
#pragma unroll
    for (int jj = 0; jj < 2; jj++)
      async_load16(ksrc[jj] + (size_t)g0 * 16384, kdst[jj]);
    *(bf16x8*)(vdst[0]) = v0;   // compiler inserts precise vmcnt before these
    *(bf16x8*)(vdst[1]) = v1;
  }

  for (int it = 0; it < L; it++) {
    const int cur = it & 1, nxt = cur ^ 1;
    const int cu16 = cur << 14;
    asm volatile("s_waitcnt lgkmcnt(0)" ::: "memory");  // publish V ds_writes
    asm volatile("s_barrier" ::: "memory");             // (A) prev reads done
    const bool pf = (it + 1 < L);
    int gn = 0;
    if (pf) {
      gn = ck ? (c0 + it + 1) : min(it + 1, c0 > 0 ? c0 - 1 : 0);
#pragma unroll
      for (int jj = 0; jj < 2; jj++)
        async_load16(ksrc[jj] + (size_t)gn * 16384, kdst[jj] + nxt * 16384);
      asm volatile("s_waitcnt vmcnt(2)" ::: "memory");  // K(it) retired; K(it+1) in flight
    } else {
      asm volatile("s_waitcnt vmcnt(0)" ::: "memory");
    }
    asm volatile("s_barrier" ::: "memory");             // (B) buf[cur] resident

    // ---- QK^T: 32 q rows x 32 keys ----
    floatx4 sacc[2][2] = {};
    const char* kA = kA0 + cu16;
    const char* kB = kB0 + cu16;
    __builtin_amdgcn_s_setprio(1);
#pragma unroll
    for (int kc = 0; kc < 4; kc++) {
      bf16x8 qfr[2];
#pragma unroll
      for (int mt = 0; mt < 2; mt++)
        qfr[mt] = *(const bf16x8*)(qb + (size_t)(b * 2048 + q0 + mt * 16 + l16) * 2048 +
                                   h * 128 + kc * 32 + quad * 8);
      const char* kp = (kc & 1) ? kB : kA;
      bf16x8 bf0 = *(const bf16x8*)(kp + (kc >> 1) * 128);
      bf16x8 bf1 = *(const bf16x8*)(kp + 4096 + (kc >> 1) * 128);
#pragma unroll
      for (int mt = 0; mt < 2; mt++) {
        sacc[mt][0] = MFMA16x16x32(qfr[mt], bf0, sacc[mt][0], 0, 0, 0);
        sacc[mt][1] = MFMA16x16x32(qfr[mt], bf1, sacc[mt][1], 0, 0, 0);
      }
    }
    __builtin_amdgcn_s_setprio(0);

    // V(it+1) gloads issued mid-iter (shortens reg liveness; latency hides under PV)
    bf16x8 vr0, vr1;
    if (pf) {
      vr0 = *(const bf16x8*)(vsrc[0] + gn * 32);
      vr1 = *(const bf16x8*)(vsrc[1] + gn * 32);
    }

    // ---- softmax: P = exp2(S), diag/validity masked ----
    const int gq = ck ? (c0 + it) : it;
    const bool diag = (ck == 1) && (it == L - 1);
    const bool inval = (ck == 0) && (it >= c0);
#pragma unroll
    for (int mt = 0; mt < 2; mt++)
#pragma unroll
      for (int r = 0; r < 4; r++) {
        const int qg = q0 + mt * 16 + quad * 4 + r;
#pragma unroll
        for (int nt = 0; nt < 2; nt++) {
          float p = __builtin_exp2f(sacc[mt][nt][r]);
          if (diag) { int keyg = gq * 32 + nt * 16 + l16; p = (keyg <= qg) ? p : 0.f; }
          if (inval) p = 0.f;
          char* w = (r & 1) ? pwO : pwE;
          *(__bf16*)(w + mt * 1024 + r * 64 + ((nt ^ ((r >> 1) & 1)) * 32)) = (__bf16)p;
        }
      }

    // ---- P @ V (+ ones for row sums); own-wave Ps & own-chunk Vt cols ----
    __builtin_amdgcn_s_setprio(1);
    bf16x8 pa[2];
#pragma unroll
    for (int mt = 0; mt < 2; mt++) {
      pa[mt] = *(const bf16x8*)(prd + mt * 1024);
      lsum[mt] = MFMA16x16x32(pa[mt], ones, lsum[mt], 0, 0, 0);
    }
    const char* vv = vrd0 + cu16;
#pragma unroll
    for (int dt = 0; dt < 8; dt++) {
      bf16x8 vf = *(const bf16x8*)(vv + dt * 2048);
      o[0][dt] = MFMA16x16x32(pa[0], vf, o[0][dt], 0, 0, 0);
      o[1][dt] = MFMA16x16x32(pa[1], vf, o[1][dt], 0, 0, 0);
    }
    __builtin_amdgcn_s_setprio(0);

    // V(it+1) regs -> Vt[nxt] (auto vmcnt wait; targets buffer not read this iter)
    if (pf) {
      *(bf16x8*)(vdst[0] + nxt * 16384) = vr0;
      *(bf16x8*)(vdst[1] + nxt * 16384) = vr1;
    }
  }

  // ---- intra-WG merge: chunk1 publishes partials via dead Ks/Vt, chunk0 reduces ----
  asm volatile("s_barrier" ::: "memory");  // all PV done; Ks/Vt dead
  {
    char* mo = (hw < 2) ? ((char*)Ks + hw * 16384) : ((char*)Vt + (hw - 2) * 16384);
    char* ml = (char*)Ps + (4 + hw) * 2048;
    if (ck == 1) {
#pragma unroll
      for (int mt = 0; mt < 2; mt++) {
#pragma unroll
        for (int dt = 0; dt < 8; dt++)
          *(floatx4*)(mo + ((mt * 8 + dt) * 64 + lane) * 16) = o[mt][dt];
        *(floatx4*)(ml + (mt * 64 + lane) * 16) = lsum[mt];
      }
    }
    asm volatile("s_waitcnt lgkmcnt(0)" ::: "memory");
    asm volatile("s_barrier" ::: "memory");
    if (ck == 0) {
#pragma unroll
      for (int mt = 0; mt < 2; mt++) {
        lsum[mt] += *(const floatx4*)(ml + (mt * 64 + lane) * 16);
        float inv[4];
#pragma unroll
        for (int r = 0; r < 4; r++) inv[r] = 1.f / lsum[mt][r];
#pragma unroll
        for (int dt = 0; dt < 8; dt++) {
          floatx4 op = *(const floatx4*)(mo + ((mt * 8 + dt) * 64 + lane) * 16);
#pragma unroll
          for (int r = 0; r < 4; r++) {
            int qg = q0 + mt * 16 + quad * 4 + r;
            yb[(size_t)(b * 2048 + qg) * 2048 + h * 128 + dt * 16 + l16] =
                (__bf16)((o[mt][dt][r] + op[r]) * inv[r]);
          }
        }
      }
    }
  }
}

// ---------------- host ----------------
extern "C" void kernel_launch(void* const* d_in, const int* in_sizes, int n_in,
                              void* d_out, int out_size, void* d_ws, size_t ws_size,
                              hipStream_t stream) {
  const float* x  = (const float*)d_in[0];
  const float* fc = (const float*)d_in[1];
  const float* fs = (const float*)d_in[2];
  const float* wq = (const float*)d_in[3];
  const float* wk = (const float*)d_in[4];
  const float* wv = (const float*)d_in[5];
  const float* wo = (const float*)d_in[6];
  float* out = (float*)d_out;
  char* ws = (char*)d_ws;

  __bf16* xb   = (__bf16*)(ws);              // 4096x2048 bf16
  __bf16* wqkv = (__bf16*)(ws + 16777216);   // 3072x2048 bf16 (wq|wk|wv)
  __bf16* wob  = (__bf16*)(ws + 29360128);   // 2048x2048 bf16
  __bf16* qbuf = (__bf16*)(ws + 37748736);   // 4096x2048 bf16 (roped, pre-scaled)
  __bf16* kbuf = (__bf16*)(ws + 54525952);   // 4096x512 bf16 (roped)
  __bf16* vtg  = (__bf16*)(ws + 58720256);   // 1024x2048 bf16 (V^T per b,kvh)
  __bf16* ybuf = (__bf16*)(ws + 62914560);   // 4096x2048 bf16

  // one merged cast launch (dst regions contiguous from ws+0)
  cast_all_kernel<<<18432, 256, 0, stream>>>(x, wq, wk, wv, wo, xb);

  // QKV projection with fused RoPE + transposed-V epilogue (M=4096, N=3072, K=2048)
  gemm_bt<1><<<dim3(24, 32), 256, 0, stream>>>(xb, wqkv, nullptr, fc, fs,
                                               qbuf, kbuf, vtg, 4096, 3072, 2048);

  // flash attention: 512 WGs x 512 thr, intra-WG split-KV, LDS merge
  attn_kernel<<<dim3(512), 512, 0, stream>>>(qbuf, kbuf, vtg, ybuf);

  // output projection: out = y @ wo^T (M=4096, N=2048, K=2048)
  gemm_bt<0><<<dim3(16, 32), 256, 0, stream>>>(ybuf, wob, out, nullptr, nullptr,
                                               nullptr, nullptr, nullptr, 4096, 2048, 2048);
}

// Round 5
// 304.349 us; speedup vs baseline: 1.3947x; 1.3947x over previous
//
#include <hip/hip_runtime.h>

typedef __attribute__((ext_vector_type(8))) __bf16 bf16x8;
typedef __attribute__((ext_vector_type(4))) __bf16 bf16x4;
typedef __attribute__((ext_vector_type(4))) float floatx4;

#define MFMA16x16x32 __builtin_amdgcn_mfma_f32_16x16x32_bf16

// async 16B/lane global->LDS; LDS dest = wave-uniform base + lane*16.
__device__ __forceinline__ void async_load16(const void* g, void* l) {
  __builtin_amdgcn_global_load_lds((const __attribute__((address_space(1))) void*)g,
                                   (__attribute__((address_space(3))) void*)l, 16, 0, 0);
}

// ---------------- merged cast fp32 -> bf16 for all 5 inputs ----------------
__global__ __launch_bounds__(256) void cast_all_kernel(const float* __restrict__ x,
                                                       const float* __restrict__ wq,
                                                       const float* __restrict__ wk,
                                                       const float* __restrict__ wv,
                                                       const float* __restrict__ wo,
                                                       __bf16* __restrict__ dst) {
  int i = blockIdx.x * blockDim.x + threadIdx.x;  // float4 units
  const float* src;
  int off;
  if (i < 2097152)      { src = x;  off = 0; }
  else if (i < 3145728) { src = wq; off = 2097152; }
  else if (i < 3407872) { src = wk; off = 3145728; }
  else if (i < 3670016) { src = wv; off = 3407872; }
  else                  { src = wo; off = 3670016; }
  float4 v = ((const float4*)src)[i - off];
  bf16x4 o;
  o[0] = (__bf16)v.x; o[1] = (__bf16)v.y; o[2] = (__bf16)v.z; o[3] = (__bf16)v.w;
  *(bf16x4*)(dst + (size_t)i * 4) = o;
}

// ---------------- GEMM: C(M,N) = A(M,K) @ B(N,K)^T, bf16 in ----------------
// 256 x BN tile, 8 waves (2M x 4N: per-wave 128 x BN/4), BK=64, counted-vmcnt
// 2-K-step-ahead pipeline (T4: vmcnt never drains mid-loop; staging of K-step
// s+2 overlaps ~2 full iterations of compute). LDS double-buffered; same
// XOR-swizzle staging/read algebra as the verified 128-tile kernel.
// MODE 0: fp32 C store. MODE 1: fused epilogue (RoPE Q/K + LDS-transposed V).
template <int MODE, int BN>
__global__ __launch_bounds__(512, 1) void gemm_bt(const __bf16* __restrict__ A,
                                                  const __bf16* __restrict__ Bw,
                                                  float* __restrict__ C,
                                                  const float* __restrict__ cs,
                                                  const float* __restrict__ sn,
                                                  __bf16* __restrict__ qb,
                                                  __bf16* __restrict__ kb,
                                                  __bf16* __restrict__ vtg,
                                                  int M, int N, int K) {
  constexpr int NW = BN / 4;        // per-wave N extent (48 or 32)
  constexpr int NF = NW / 16;       // n-frags per wave (3 or 2)
  constexpr int NBI = BN / 64;      // B staging instrs per wave (3 or 2)
  __shared__ __bf16 As[2][256][64];
  __shared__ __bf16 Bs[2][BN][64];
  const int tid = threadIdx.x;
  const int wave = tid >> 6, lane = tid & 63;
  const int quad = lane >> 4, l16 = lane & 15;
  const int wm2 = wave >> 2, wn4 = wave & 3;       // 2M x 4N wave grid
  const int lr = lane >> 3, ls = lane & 7;
  const int segg = ls ^ lr;

  // bijective XCD swizzle (gridDim.x % 8 == 0 for both call sites)
  const int nwg = gridDim.x;
  const int wg = (blockIdx.x & 7) * (nwg >> 3) + (blockIdx.x >> 3);
  const int GY = M >> 8;
  const int by = wg % GY, bx = wg / GY;
  const int row0 = by * 256, col0 = bx * BN;

  floatx4 acc[8][NF] = {};
  const __bf16* Ab = A + (size_t)row0 * K + segg * 8;
  const __bf16* Bb = Bw + (size_t)col0 * K + segg * 8;

  auto stage = [&](int sb, int k0) {
#pragma unroll
    for (int i = 0; i < 4; i++)
      async_load16(Ab + (size_t)(wave * 32 + i * 8 + lr) * K + k0,
                   &As[sb][wave * 32 + i * 8][0]);
#pragma unroll
    for (int j = 0; j < NBI; j++)
      async_load16(Bb + (size_t)(wave * (BN / 8) + j * 8 + lr) * K + k0,
                   &Bs[sb][wave * (BN / 8) + j * 8][0]);
  };

  const int NS = K >> 6;
  stage(0, 0);
  stage(1, 64);

#pragma unroll 2
  for (int s = 0; s < NS; s++) {
    const int c = s & 1;
    // counted wait: newest (4+NBI) loads (= stage(s+1)) may remain in flight;
    // everything older (incl. stage(s)) has landed. Last iter: full drain.
    if (s == NS - 1) {
      asm volatile("s_waitcnt vmcnt(0)" ::: "memory");
    } else if constexpr (NBI == 3) {
      asm volatile("s_waitcnt vmcnt(7)" ::: "memory");
    } else {
      asm volatile("s_waitcnt vmcnt(6)" ::: "memory");
    }
    __builtin_amdgcn_s_barrier();  // (a) all waves' buf[c] slices resident

    bf16x8 af[2][8], bfr[2][NF];
#pragma unroll
    for (int kk = 0; kk < 2; kk++) {
#pragma unroll
      for (int mt = 0; mt < 8; mt++) {
        int row = wm2 * 128 + mt * 16 + l16;
        int seg = (kk * 4 + quad) ^ (row & 7);
        af[kk][mt] = *(const bf16x8*)&As[c][row][seg * 8];
      }
#pragma unroll
      for (int nt = 0; nt < NF; nt++) {
        int row = wn4 * NW + nt * 16 + l16;
        int seg = (kk * 4 + quad) ^ (row & 7);
        bfr[kk][nt] = *(const bf16x8*)&Bs[c][row][seg * 8];
      }
    }
    asm volatile("s_waitcnt lgkmcnt(0)" ::: "memory");  // frags in regs
    __builtin_amdgcn_s_barrier();  // (b) ALL waves done reading buf[c]
    if (s + 2 < NS) stage(c, (s + 2) * 64);  // DMA into freed buf[c]
    __builtin_amdgcn_s_setprio(1);
#pragma unroll
    for (int kk = 0; kk < 2; kk++)
#pragma unroll
      for (int mt = 0; mt < 8; mt++)
#pragma unroll
        for (int nt = 0; nt < NF; nt++)
          acc[mt][nt] = MFMA16x16x32(af[kk][mt], bfr[kk][nt], acc[mt][nt], 0, 0, 0);
    __builtin_amdgcn_s_setprio(0);
  }

  if (MODE == 0) {
#pragma unroll
    for (int mt = 0; mt < 8; mt++)
#pragma unroll
      for (int nt = 0; nt < NF; nt++)
#pragma unroll
        for (int r = 0; r < 4; r++) {
          int row = row0 + wm2 * 128 + mt * 16 + quad * 4 + r;
          int col = col0 + wn4 * NW + nt * 16 + l16;
          C[(size_t)row * N + col] = acc[mt][nt][r];
        }
  } else {
    // ---- Q / K epilogue (RoPE; Q pre-scaled by (1/sqrt(128))*log2(e)) ----
#pragma unroll
    for (int mt = 0; mt < 8; mt++)
#pragma unroll
      for (int nt = 0; nt < NF; nt++) {
        const int cbase = col0 + wn4 * NW + nt * 16;  // uniform per (wave,nt)
        if (cbase < 2560) {
          const int c = cbase + l16;
#pragma unroll
          for (int r = 0; r < 4; r++) {
            int row = row0 + wm2 * 128 + mt * 16 + quad * 4 + r;
            int t = row & 2047;
            float v = acc[mt][nt][r];
            float vp = __shfl_xor(v, 1);  // RoPE pair partner (col ^ 1)
            int i = (c & 127) >> 1;
            float co = cs[t * 64 + i], si = sn[t * 64 + i];
            float rv = v * co + ((c & 1) ? vp : -vp) * si;
            if (cbase < 2048) {
              qb[(size_t)row * 2048 + c] = (__bf16)(rv * 0.1275411391f);
            } else {
              kb[(size_t)row * 512 + c - 2048] = (__bf16)rv;
            }
          }
        }
      }
    // ---- V epilogue: per-wave LDS transpose -> contiguous 16B stores ----
    // As is dead (all waves' reads drained before last mid-barrier; no DMA
    // outstanding past iter NS-1's vmcnt(0)). Per-wave private 4KB slice.
    __bf16* Vl = &As[0][0][0] + wave * 2048;  // [16 vd][128 t]
    const int brow = row0 + wm2 * 128;        // 128 rows, single batch
    const int bb = brow >> 11, trow = brow & 2047;
#pragma unroll
    for (int nt = 0; nt < NF; nt++) {
      const int cbase = col0 + wn4 * NW + nt * 16;
      if (cbase >= 2560) {
#pragma unroll
        for (int mt = 0; mt < 8; mt++)
#pragma unroll
          for (int r = 0; r < 4; r++)
            Vl[l16 * 128 + mt * 16 + quad * 4 + r] = (__bf16)acc[mt][nt][r];
        asm volatile("" ::: "memory");
        const int vB = cbase - 2560;
#pragma unroll
        for (int p = 0; p < 4; p++) {
          int vd = p * 4 + (lane >> 4);
          int t0 = (lane & 15) * 8;
          bf16x8 val = *(const bf16x8*)&Vl[vd * 128 + t0];
          *(bf16x8*)&vtg[((size_t)bb * 512 + vB + vd) * 2048 + trow + t0] = val;
        }
        asm volatile("" ::: "memory");
      }
    }
  }
}

// ---------------- Flash attention, causal, GQA; double-buffered K/V ----------------
// Proven R3 version (77.5 us): counted-vmcnt pipeline, hoisted swizzled LDS bases.
__global__ __launch_bounds__(256, 2) void attn_kernel(const __bf16* __restrict__ qb,
                                                      const __bf16* __restrict__ kb,
                                                      const __bf16* __restrict__ vtg,
                                                      __bf16* __restrict__ yb) {
  const int id = blockIdx.x;
  const int q1 = id >> 8;              // 0..1
  const int cc = id & 255;
  const int kvh = cc & 3;
  const int b = (cc >> 2) & 1;
  const int s5 = (cc >> 3) & 31;
  const int tile = q1 ? (63 - s5) : s5;  // bijective over 0..63; pairs co-resident
  const int tid = threadIdx.x, wave = tid >> 6, lane = tid & 63;
  const int h = kvh * 4 + wave;
  const int quad = lane >> 4, l16 = lane & 15;
  const int q0 = tile * 32;
  __shared__ __bf16 Ks[2][64][128];      // [buf][key][dim], swizzled (32 KB)
  __shared__ __bf16 Vt[2][128][64];      // [buf][dim][key], swizzled (32 KB)
  __shared__ __bf16 Ps[4][2][16][64];    // per-wave, per-m-tile P strip (16 KB)
  const __bf16* kbase = kb + (size_t)b * 2048 * 512 + kvh * 128;
  const __bf16* vbase = vtg + ((size_t)b * 512 + kvh * 128) * 2048;

  // ---- hoisted lane-dependent LDS byte bases (loop-invariant) ----
  const int u16   = (quad ^ (l16 & 3)) * 16;
  const int b2_64 = (l16 & 4) ? 64 : 0;
  char* const ksb = (char*)Ks;
  char* const vtb = (char*)Vt;
  char* const psb = (char*)Ps + wave * 4096;
  char* const kA0 = ksb + l16 * 256 + u16 + b2_64;   // K frag, kc even, buf0
  char* const kB0 = kA0 + 64 - 2 * b2_64;            // K frag, kc odd,  buf0
  char* const kA1 = kA0 + 16384;
  char* const kB1 = kB0 + 16384;
  char* const vA0 = vtb + l16 * 128 + u16 + b2_64;   // V frag, c2=0, buf0
  char* const vB0 = vA0 + 64 - 2 * b2_64;            // V frag, c2=1, buf0
  char* const vA1 = vA0 + 16384;
  char* const vB1 = vB0 + 16384;
  char* const prA = psb + l16 * 128 + u16 + b2_64;   // Ps read, c2=0 (+mt*2048)
  char* const prB = prA + 64 - 2 * b2_64;            // Ps read, c2=1
  const int h16 = (l16 & 8) ? 16 : 0;
  const int q64 = (quad & 1) * 64;
  char* const pw00 = psb + quad * 512 + (l16 & 7) * 2 + h16 + q64;         // r even, nt<2
  char* const pw10 = psb + quad * 512 + (l16 & 7) * 2 + (16 - h16) + q64;  // r odd,  nt<2
  char* const pw01 = pw00 + 64 - 2 * q64;                                  // r even, nt>=2
  char* const pw11 = pw10 + 64 - 2 * q64;                                  // r odd,  nt>=2

  // ---- hoisted staging source pointers (global) ----
  const int klr4 = lane >> 4, kls = lane & 15;
  const int vlr8 = lane >> 3, vls = lane & 7;
  const __bf16* ksrc[4];
  const __bf16* vsrc[4];
#pragma unroll
  for (int i = 0; i < 4; i++) {
    int row = (wave * 4 + i) * 4 + klr4;
    ksrc[i] = kbase + (size_t)row * 512 + (kls ^ (row & 7)) * 8;
    int d = (wave * 4 + i) * 8 + vlr8;
    vsrc[i] = vbase + (size_t)d * 2048 + (vls ^ (d & 7)) * 8;
  }
  char* const kdst = ksb + wave * 4096;
  char* const vdst = vtb + wave * 4096;

  auto stage = [&](int pb, int s0) {
#pragma unroll
    for (int i = 0; i < 4; i++)   // K: 64 keys x 128 dims
      async_load16(ksrc[i] + (size_t)s0 * 512, kdst + pb * 16384 + i * 1024);
#pragma unroll
    for (int i = 0; i < 4; i++)   // Vt: 128 dims x 64 keys
      async_load16(vsrc[i] + s0, vdst + pb * 16384 + i * 1024);
  };

  bf16x8 qf[2][4];
#pragma unroll
  for (int mt = 0; mt < 2; mt++)
#pragma unroll
    for (int kc = 0; kc < 4; kc++)
      qf[mt][kc] = *(const bf16x8*)(qb + (size_t)(b * 2048 + q0 + mt * 16 + l16) * 2048 +
                                    h * 128 + kc * 32 + quad * 8);
  bf16x8 ones;
#pragma unroll
  for (int j = 0; j < 8; j++) ones[j] = (__bf16)1.0f;
  floatx4 o[2][8] = {};
  floatx4 lsum[2] = {};
  const int nblocks = (tile + 2) >> 1;  // ceil((q0+32)/64)

  stage(0, 0);  // prologue; residency enforced by iter-0 vmcnt+barrier

  for (int it = 0; it < nblocks; it++) {
    const int cur = it & 1;
    const int s0 = it * 64;
    // (a) all waves done READING buf[cur^1] (prev iter) -> safe to DMA into it
    asm volatile("s_barrier" ::: "memory");
    if (it + 1 < nblocks) {
      stage(cur ^ 1, s0 + 64);  // prefetch next tile; stays in flight over compute
      asm volatile("s_waitcnt vmcnt(8)" ::: "memory");  // my buf[cur] loads retired
    } else {
      asm volatile("s_waitcnt vmcnt(0)" ::: "memory");
    }
    // (b) every wave's buf[cur] slice resident
    asm volatile("s_barrier" ::: "memory");
    const char* kA = cur ? kA1 : kA0;
    const char* kB = cur ? kB1 : kB0;
    const char* vA = cur ? vA1 : vA0;
    const char* vB = cur ? vB1 : vB0;
    // QK^T: 32 q rows x 64 keys (K-frags shared by both m-tiles)
    floatx4 sacc[2][4] = {};
    __builtin_amdgcn_s_setprio(1);
#pragma unroll
    for (int kc = 0; kc < 4; kc++) {
      const char* kbp = (kc & 1) ? kB : kA;
      bf16x8 bfr[4];
#pragma unroll
      for (int nt = 0; nt < 4; nt++)
        bfr[nt] = *(const bf16x8*)(kbp + nt * 4096 + (kc >> 1) * 128);
#pragma unroll
      for (int mt = 0; mt < 2; mt++)
#pragma unroll
        for (int nt = 0; nt < 4; nt++)
          sacc[mt][nt] = MFMA16x16x32(qf[mt][kc], bfr[nt], sacc[mt][nt], 0, 0, 0);
    }
    __builtin_amdgcn_s_setprio(0);
    // P = exp2(S) (scale pre-folded into Q), masked on diagonal block
    const bool diag = (it == nblocks - 1);
#pragma unroll
    for (int mt = 0; mt < 2; mt++)
#pragma unroll
      for (int r = 0; r < 4; r++) {
        const int qg = q0 + mt * 16 + quad * 4 + r;
#pragma unroll
        for (int nt = 0; nt < 4; nt++) {
          float p = __builtin_exp2f(sacc[mt][nt][r]);
          if (diag) { int keyg = s0 + nt * 16 + l16; p = (keyg <= qg) ? p : 0.f; }
          char* w = (r & 1) ? ((nt < 2) ? pw10 : pw11) : ((nt < 2) ? pw00 : pw01);
          *(__bf16*)(w + mt * 2048 + r * 128 + ((nt & 1) ^ (r >> 1)) * 32) = (__bf16)p;
        }
      }
    // P @ V (+ ones for row sums). Same-wave Ps write->read: no barrier.
    __builtin_amdgcn_s_setprio(1);
#pragma unroll
    for (int c2 = 0; c2 < 2; c2++) {
      const char* pr = c2 ? prB : prA;
      const char* vv = c2 ? vB : vA;
      bf16x8 pa[2];
#pragma unroll
      for (int mt = 0; mt < 2; mt++) {
        pa[mt] = *(const bf16x8*)(pr + mt * 2048);
        lsum[mt] = MFMA16x16x32(pa[mt], ones, lsum[mt], 0, 0, 0);
      }
#pragma unroll
      for (int dt = 0; dt < 8; dt++) {
        bf16x8 vf = *(const bf16x8*)(vv + dt * 2048);
#pragma unroll
        for (int mt = 0; mt < 2; mt++)
          o[mt][dt] = MFMA16x16x32(pa[mt], vf, o[mt][dt], 0, 0, 0);
      }
    }
    __builtin_amdgcn_s_setprio(0);
  }
#pragma unroll
  for (int mt = 0; mt < 2; mt++) {
    float inv[4];
#pragma unroll
    for (int r = 0; r < 4; r++) inv[r] = 1.f / lsum[mt][r];
#pragma unroll
    for (int dt = 0; dt < 8; dt++)
#pragma unroll
      for (int r = 0; r < 4; r++) {
        int qg = q0 + mt * 16 + quad * 4 + r;
        yb[(size_t)(b * 2048 + qg) * 2048 + h * 128 + dt * 16 + l16] =
            (__bf16)(o[mt][dt][r] * inv[r]);
      }
  }
}

// ---------------- host ----------------
extern "C" void kernel_launch(void* const* d_in, const int* in_sizes, int n_in,
                              void* d_out, int out_size, void* d_ws, size_t ws_size,
                              hipStream_t stream) {
  const float* x  = (const float*)d_in[0];
  const float* fc = (const float*)d_in[1];
  const float* fs = (const float*)d_in[2];
  const float* wq = (const float*)d_in[3];
  const float* wk = (const float*)d_in[4];
  const float* wv = (const float*)d_in[5];
  const float* wo = (const float*)d_in[6];
  float* out = (float*)d_out;
  char* ws = (char*)d_ws;

  __bf16* xb   = (__bf16*)(ws);              // 4096x2048 bf16
  __bf16* wqkv = (__bf16*)(ws + 16777216);   // 3072x2048 bf16 (wq|wk|wv)
  __bf16* wob  = (__bf16*)(ws + 29360128);   // 2048x2048 bf16
  __bf16* qbuf = (__bf16*)(ws + 37748736);   // 4096x2048 bf16 (roped, pre-scaled)
  __bf16* kbuf = (__bf16*)(ws + 54525952);   // 4096x512 bf16 (roped)
  __bf16* vtg  = (__bf16*)(ws + 58720256);   // 1024x2048 bf16 (V^T per b,kvh)
  __bf16* ybuf = (__bf16*)(ws + 62914560);   // 4096x2048 bf16

  // one merged cast launch (dst regions contiguous from ws+0)
  cast_all_kernel<<<18432, 256, 0, stream>>>(x, wq, wk, wv, wo, xb);

  // QKV projection, 256x192 tiles -> 256 WGs (1/CU), fused RoPE/V epilogue
  gemm_bt<1, 192><<<256, 512, 0, stream>>>(xb, wqkv, nullptr, fc, fs,
                                           qbuf, kbuf, vtg, 4096, 3072, 2048);

  // flash attention: 512 4-wave WGs, 32 q-rows/wave, counted-vmcnt pipeline
  attn_kernel<<<512, 256, 0, stream>>>(qbuf, kbuf, vtg, ybuf);

  // output projection, 256x128 tiles -> 256 WGs (1/CU)
  gemm_bt<0, 128><<<256, 512, 0, stream>>>(ybuf, wob, out, nullptr, nullptr,
                                           nullptr, nullptr, nullptr, 4096, 2048, 2048);
}